// Round 1
// baseline (516.786 us; speedup 1.0000x reference)
//
#include <hip/hip_runtime.h>
#include <hip/hip_bf16.h>
#include <stdint.h>

// Problem constants (fixed by the reference)
#define NE      1048576     // edges
#define NNODES  65536       // B*N
#define DIMV    64          // embedding dim
#define HDIM    256         // SwiGLU hidden width

typedef __bf16 bf16x8 __attribute__((ext_vector_type(8)));
typedef float  f32x4  __attribute__((ext_vector_type(4)));

__device__ __forceinline__ unsigned short f2bf(float f) {
    union { float f; uint32_t u; } v; v.f = f;
    return (unsigned short)((v.u + 0x7fffu + ((v.u >> 16) & 1u)) >> 16);  // RNE
}

// ---------------- prep 1: node features fp32 -> bf16 table ----------------
__global__ void prep_x_kernel(const float* __restrict__ x, unsigned short* __restrict__ xb) {
    int i = blockIdx.x * blockDim.x + threadIdx.x;
    const int total = NNODES * DIMV / 4;
    for (; i < total; i += gridDim.x * blockDim.x) {
        float4 v = ((const float4*)x)[i];
        ushort4 o;
        o.x = f2bf(v.x); o.y = f2bf(v.y); o.z = f2bf(v.z); o.w = f2bf(v.w);
        ((ushort4*)xb)[i] = o;
    }
}

// ------- prep 2: weights -> transposed, XOR-swizzled bf16 LDS images -------
// Image layout (per matrix, 65536 B): for column h (0..255), 16B chunk cc (0..15)
// holding W[k][h] for k = cc*8 .. cc*8+7, stored at byte h*256 + ((cc*16) ^ ((h&7)<<4)).
__global__ void prep_w_kernel(const float* __restrict__ wg, const float* __restrict__ wi,
                              unsigned short* __restrict__ img) {
    int t = blockIdx.x * blockDim.x + threadIdx.x;
    if (t >= 2 * HDIM * 16) return;
    int mat = t >> 12;
    int h   = (t >> 4) & 255;
    int cc  = t & 15;
    const float* w = mat ? wi : wg;
    unsigned short tmp[8] __attribute__((aligned(16)));
    #pragma unroll
    for (int j = 0; j < 8; ++j)
        tmp[j] = f2bf(w[(cc * 8 + j) * HDIM + h]);
    int byteoff = mat * 65536 + h * 256 + ((cc * 16) ^ ((h & 7) << 4));
    *(uint4*)((char*)img + byteoff) = *(const uint4*)tmp;
}

// ---------------- main: fused gather + dual GEMM + SwiGLU + reduce ----------------
// Block: 512 threads (8 waves). Wave handles 64 edges (4 M-frags of 16).
// Full Wg+Wi (bf16, transposed, swizzled) resident in 128 KiB LDS.
// A-fragments gathered directly global->VGPR (16 B per lane per frag).
__global__ __launch_bounds__(512, 2) void edge_swiglu_kernel(
    const unsigned short* __restrict__ xb,
    const unsigned short* __restrict__ wimg,
    const int* __restrict__ eidx,
    const float* __restrict__ wo,
    float* __restrict__ out)
{
    __shared__ char wlds[131072];

    const int tid  = threadIdx.x;
    const int lane = tid & 63;
    const int wave = tid >> 6;
    const int r = lane & 15;       // MFMA col (h) / A row (edge) selector
    const int q = lane >> 4;       // k-group selector

    // stage weight images -> LDS (linear copy; image is pre-swizzled)
    {
        const uint4* src = (const uint4*)wimg;
        uint4* dst = (uint4*)wlds;
        #pragma unroll
        for (int i = 0; i < 16; ++i) {
            int idx = tid + i * 512;
            dst[idx] = src[idx];
        }
    }

    const int eb = blockIdx.x * 512 + wave * 64;

    // gather A fragments: edge features = concat(x[scope], x[goal]) in bf16
    // A-frag layout for mfma_f32_16x16x32_bf16: row = lane&15, k = (lane>>4)*8 + j
    bf16x8 a[4][4];
    #pragma unroll
    for (int m = 0; m < 4; ++m) {
        int e  = eb + m * 16 + r;
        int sc = eidx[e];
        int gl = eidx[NE + e];
        #pragma unroll
        for (int ks = 0; ks < 4; ++ks) {
            int node = (ks < 2) ? sc : gl;                 // k<64 -> scope, else goal
            const unsigned short* p = xb + node * DIMV + (ks & 1) * 32 + q * 8;
            a[m][ks] = *(const bf16x8*)p;
        }
    }

    // per-lane w_out values for each N-frag: h = nf*16 + r
    float wo_r[16];
    #pragma unroll
    for (int nf = 0; nf < 16; ++nf) wo_r[nf] = wo[nf * 16 + r];

    float part[4][4];
    #pragma unroll
    for (int m = 0; m < 4; ++m)
        #pragma unroll
        for (int j = 0; j < 4; ++j) part[m][j] = 0.0f;

    __syncthreads();

    #pragma unroll
    for (int nf = 0; nf < 16; ++nf) {
        const int h      = nf * 16 + r;
        const int rowoff = h << 8;              // h * 256 bytes
        const int swz    = (h & 7) << 4;
        bf16x8 bg[4], bi[4];
        #pragma unroll
        for (int ks = 0; ks < 4; ++ks) {
            int cb = (ks * 64 + q * 16) ^ swz;  // byte offset of this lane's 16B of k
            bg[ks] = *(const bf16x8*)(wlds + rowoff + cb);
            bi[ks] = *(const bf16x8*)(wlds + 65536 + rowoff + cb);
        }
        f32x4 accG[4], accI[4];
        const f32x4 zero = {0.0f, 0.0f, 0.0f, 0.0f};
        #pragma unroll
        for (int m = 0; m < 4; ++m) { accG[m] = zero; accI[m] = zero; }
        #pragma unroll
        for (int ks = 0; ks < 4; ++ks) {
            #pragma unroll
            for (int m = 0; m < 4; ++m) {
                accG[m] = __builtin_amdgcn_mfma_f32_16x16x32_bf16(a[m][ks], bg[ks], accG[m], 0, 0, 0);
                accI[m] = __builtin_amdgcn_mfma_f32_16x16x32_bf16(a[m][ks], bi[ks], accI[m], 0, 0, 0);
            }
        }
        const float woh = wo_r[nf];
        #pragma unroll
        for (int m = 0; m < 4; ++m) {
            #pragma unroll
            for (int j = 0; j < 4; ++j) {
                float g  = accG[m][j];
                float iv = accI[m][j];
                float sg = g * __builtin_amdgcn_rcpf(1.0f + __expf(-g));  // silu
                part[m][j] = __builtin_fmaf(sg * iv, woh, part[m][j]);
            }
        }
    }

    // reduce over h across the 16 low lanes, then store 4 edges per (q,m)
    #pragma unroll
    for (int m = 0; m < 4; ++m) {
        f32x4 v;
        #pragma unroll
        for (int j = 0; j < 4; ++j) {
            float s = part[m][j];
            s += __shfl_xor(s, 1);
            s += __shfl_xor(s, 2);
            s += __shfl_xor(s, 4);
            s += __shfl_xor(s, 8);
            v[j] = s;
        }
        if (r == 0)
            *(f32x4*)(out + eb + m * 16 + q * 4) = v;
    }
}

extern "C" void kernel_launch(void* const* d_in, const int* in_sizes, int n_in,
                              void* d_out, int out_size, void* d_ws, size_t ws_size,
                              hipStream_t stream) {
    const float* x   = (const float*)d_in[0];   // [65536, 64] fp32
    const float* wg  = (const float*)d_in[1];   // [128, 256] fp32
    const float* wi  = (const float*)d_in[2];   // [128, 256] fp32
    const float* wo  = (const float*)d_in[3];   // [256] fp32
    const int*   ei  = (const int*)d_in[4];     // [2, E] int
    float* out = (float*)d_out;

    unsigned short* xb   = (unsigned short*)d_ws;                       // 8 MiB bf16 node table
    unsigned short* wimg = (unsigned short*)((char*)d_ws + 8388608);    // 128 KiB weight images

    prep_x_kernel<<<1024, 256, 0, stream>>>(x, xb);
    prep_w_kernel<<<32, 256, 0, stream>>>(wg, wi, wimg);
    edge_swiglu_kernel<<<NE / 512, 512, 0, stream>>>(xb, wimg, ei, wo, out);
}